// Round 1
// baseline (1850.452 us; speedup 1.0000x reference)
//
#include <hip/hip_runtime.h>
#include <math.h>

#define BB 4
#define SS 1024
#define HIDD 1024
#define NH 32
#define HD 32
#define RS 0.17677669529663687f   // 1/sqrt(32)

// ---------------------------------------------------------------------------
// GEMM: Y = X @ W^T + b   (X: M x 1024 row-major, W: N x 1024 row-major)
// 128x128 tile, BK=16, 256 threads, 8x8 per-thread microtile.
// Two variants differ only in epilogue.
// ---------------------------------------------------------------------------
#define BM 128
#define BN 128
#define BK 16

__global__ __launch_bounds__(256) void gemm_qkv(
    const float* __restrict__ X,
    const float* __restrict__ W0, const float* __restrict__ W1, const float* __restrict__ W2,
    const float* __restrict__ c0, const float* __restrict__ c1, const float* __restrict__ c2,
    float* __restrict__ O0, float* __restrict__ O1, float* __restrict__ O2)
{
    const int zi = blockIdx.z;
    const float* Wm = (zi == 0) ? W0 : (zi == 1 ? W1 : W2);
    const float* bm = (zi == 0) ? c0 : (zi == 1 ? c1 : c2);
    float* Om       = (zi == 0) ? O0 : (zi == 1 ? O1 : O2);

    const int i0 = blockIdx.x * BM;
    const int j0 = blockIdx.y * BN;
    const int tid = threadIdx.x;
    const int tx = tid & 15, ty = tid >> 4;
    const int m0 = tx * 8, n0 = ty * 8;

    __shared__ float As[BK][BM + 4];
    __shared__ float Bs[BK][BN + 4];

    float acc[8][8] = {};

    for (int k0 = 0; k0 < 1024; k0 += BK) {
        #pragma unroll
        for (int f0 = 0; f0 < 2; ++f0) {
            int f = tid + f0 * 256;          // 0..511
            int r = f >> 2;                  // 0..127
            int c4 = (f & 3) * 4;            // 0,4,8,12
            float4 a = *(const float4*)&X[(size_t)(i0 + r) * 1024 + k0 + c4];
            As[c4 + 0][r] = a.x; As[c4 + 1][r] = a.y;
            As[c4 + 2][r] = a.z; As[c4 + 3][r] = a.w;
            float4 w = *(const float4*)&Wm[(size_t)(j0 + r) * 1024 + k0 + c4];
            Bs[c4 + 0][r] = w.x; Bs[c4 + 1][r] = w.y;
            Bs[c4 + 2][r] = w.z; Bs[c4 + 3][r] = w.w;
        }
        __syncthreads();
        #pragma unroll
        for (int k = 0; k < BK; ++k) {
            float ar[8], br[8];
            *(float4*)&ar[0] = *(const float4*)&As[k][m0];
            *(float4*)&ar[4] = *(const float4*)&As[k][m0 + 4];
            *(float4*)&br[0] = *(const float4*)&Bs[k][n0];
            *(float4*)&br[4] = *(const float4*)&Bs[k][n0 + 4];
            #pragma unroll
            for (int mm = 0; mm < 8; ++mm)
                #pragma unroll
                for (int nn = 0; nn < 8; ++nn)
                    acc[mm][nn] += ar[mm] * br[nn];
        }
        __syncthreads();
    }

    // epilogue: write into (B, NH, S, HD) layout
    #pragma unroll
    for (int mm = 0; mm < 8; ++mm) {
        int i = i0 + m0 + mm;
        int bi = i >> 10, si = i & 1023;
        #pragma unroll
        for (int nn4 = 0; nn4 < 8; nn4 += 4) {
            int j = j0 + n0 + nn4;
            int h = j >> 5, d = j & 31;
            float4 o;
            o.x = acc[mm][nn4 + 0] + bm[j + 0];
            o.y = acc[mm][nn4 + 1] + bm[j + 1];
            o.z = acc[mm][nn4 + 2] + bm[j + 2];
            o.w = acc[mm][nn4 + 3] + bm[j + 3];
            *(float4*)&Om[(((size_t)bi * NH + h) * SS + si) * HD + d] = o;
        }
    }
}

__global__ __launch_bounds__(256) void gemm_out(
    const float* __restrict__ X, const float* __restrict__ Wm,
    const float* __restrict__ bm, const float* __restrict__ res,
    float* __restrict__ Om)
{
    const int i0 = blockIdx.x * BM;
    const int j0 = blockIdx.y * BN;
    const int tid = threadIdx.x;
    const int tx = tid & 15, ty = tid >> 4;
    const int m0 = tx * 8, n0 = ty * 8;

    __shared__ float As[BK][BM + 4];
    __shared__ float Bs[BK][BN + 4];

    float acc[8][8] = {};

    for (int k0 = 0; k0 < 1024; k0 += BK) {
        #pragma unroll
        for (int f0 = 0; f0 < 2; ++f0) {
            int f = tid + f0 * 256;
            int r = f >> 2;
            int c4 = (f & 3) * 4;
            float4 a = *(const float4*)&X[(size_t)(i0 + r) * 1024 + k0 + c4];
            As[c4 + 0][r] = a.x; As[c4 + 1][r] = a.y;
            As[c4 + 2][r] = a.z; As[c4 + 3][r] = a.w;
            float4 w = *(const float4*)&Wm[(size_t)(j0 + r) * 1024 + k0 + c4];
            Bs[c4 + 0][r] = w.x; Bs[c4 + 1][r] = w.y;
            Bs[c4 + 2][r] = w.z; Bs[c4 + 3][r] = w.w;
        }
        __syncthreads();
        #pragma unroll
        for (int k = 0; k < BK; ++k) {
            float ar[8], br[8];
            *(float4*)&ar[0] = *(const float4*)&As[k][m0];
            *(float4*)&ar[4] = *(const float4*)&As[k][m0 + 4];
            *(float4*)&br[0] = *(const float4*)&Bs[k][n0];
            *(float4*)&br[4] = *(const float4*)&Bs[k][n0 + 4];
            #pragma unroll
            for (int mm = 0; mm < 8; ++mm)
                #pragma unroll
                for (int nn = 0; nn < 8; ++nn)
                    acc[mm][nn] += ar[mm] * br[nn];
        }
        __syncthreads();
    }

    #pragma unroll
    for (int mm = 0; mm < 8; ++mm) {
        int i = i0 + m0 + mm;
        #pragma unroll
        for (int nn4 = 0; nn4 < 8; nn4 += 4) {
            int j = j0 + n0 + nn4;
            float4 r4 = *(const float4*)&res[(size_t)i * 1024 + j];
            float4 o;
            o.x = acc[mm][nn4 + 0] + bm[j + 0] + r4.x;
            o.y = acc[mm][nn4 + 1] + bm[j + 1] + r4.y;
            o.z = acc[mm][nn4 + 2] + bm[j + 2] + r4.z;
            o.w = acc[mm][nn4 + 3] + bm[j + 3] + r4.w;
            *(float4*)&Om[(size_t)i * 1024 + j] = o;
        }
    }
}

// ---------------------------------------------------------------------------
// Attention: per block = (row-half, head, batch). 256 threads, 2 rows/thread.
// Phase 1: online softmax (m, l) over all 1024 keys (whole K panel in LDS).
// Phase 2: recompute scores, write normalized probs, accumulate PV.
// ---------------------------------------------------------------------------
__global__ __launch_bounds__(256) void attn_kernel(
    const float* __restrict__ Q, const float* __restrict__ K,
    const float* __restrict__ V, const float* __restrict__ dist,
    float* __restrict__ probs, float* __restrict__ ctx)
{
    const int tile = blockIdx.x;   // 0..1 (row half)
    const int h = blockIdx.y;
    const int b = blockIdx.z;
    const int tid = threadIdx.x;
    const int r0 = tile * 512;
    const size_t bh = (size_t)(b * NH + h);
    const float* Qh = Q + bh * SS * HD;
    const float* Kh = K + bh * SS * HD;
    const float* Vh = V + bh * SS * HD;
    float* Ph = probs + bh * SS * SS;

    __shared__ float Kt[512 * HD];   // 64 KB
    __shared__ float Vt[512 * HD];   // 64 KB
    __shared__ float dl[1536];       // 6 KB  (dist_emb window, column h)

    for (int t = tid; t < 1535; t += 256)
        dl[t] = dist[(size_t)(r0 + t) * HD + h];

    // phase-1 staging: Kt = K rows [0,512), Vt = K rows [512,1024)
    for (int f = tid; f < 4096; f += 256) {
        ((float4*)Kt)[f] = ((const float4*)Kh)[f];
        ((float4*)Vt)[f] = ((const float4*)Kh)[f + 4096];
    }

    // load both q rows into registers
    float q1[32], q2[32];
    #pragma unroll
    for (int d4 = 0; d4 < 8; ++d4) {
        float4 a = ((const float4*)(Qh + (size_t)(r0 + tid) * HD))[d4];
        q1[d4 * 4 + 0] = a.x; q1[d4 * 4 + 1] = a.y;
        q1[d4 * 4 + 2] = a.z; q1[d4 * 4 + 3] = a.w;
        float4 c = ((const float4*)(Qh + (size_t)(r0 + 256 + tid) * HD))[d4];
        q2[d4 * 4 + 0] = c.x; q2[d4 * 4 + 1] = c.y;
        q2[d4 * 4 + 2] = c.z; q2[d4 * 4 + 3] = c.w;
    }
    __syncthreads();

    float m1 = -1e30f, l1 = 0.f, m2 = -1e30f, l2 = 0.f;
    #pragma unroll 1
    for (int ht = 0; ht < 2; ++ht) {
        const float* KT = ht ? Vt : Kt;
        const int jbase = ht * 512;
        #pragma unroll 2
        for (int j = 0; j < 512; ++j) {
            const float* kr = KT + j * HD;
            float a1 = 0.f, a2 = 0.f;
            #pragma unroll
            for (int d4 = 0; d4 < 8; ++d4) {
                float4 kv = ((const float4*)kr)[d4];
                a1 += q1[d4*4+0]*kv.x + q1[d4*4+1]*kv.y + q1[d4*4+2]*kv.z + q1[d4*4+3]*kv.w;
                a2 += q2[d4*4+0]*kv.x + q2[d4*4+1]*kv.y + q2[d4*4+2]*kv.z + q2[d4*4+3]*kv.w;
            }
            int jg = jbase + j;
            float s1 = (a1 + dl[tid + 1023 - jg]) * RS;
            float s2 = (a2 + dl[tid + 1279 - jg]) * RS;
            if (s1 > m1) { l1 *= __expf(m1 - s1); m1 = s1; }
            l1 += __expf(s1 - m1);
            if (s2 > m2) { l2 *= __expf(m2 - s2); m2 = s2; }
            l2 += __expf(s2 - m2);
        }
    }
    const float rl1 = 1.f / l1, rl2 = 1.f / l2;

    float c1[32] = {}, c2[32] = {};

    #pragma unroll 1
    for (int jt = 0; jt < 2; ++jt) {
        __syncthreads();
        for (int f = tid; f < 4096; f += 256) {
            if (jt) ((float4*)Kt)[f] = ((const float4*)(Kh + (size_t)jt * 512 * HD))[f];
            ((float4*)Vt)[f] = ((const float4*)(Vh + (size_t)jt * 512 * HD))[f];
        }
        __syncthreads();

        #pragma unroll 1
        for (int jj = 0; jj < 512; jj += 4) {
            float pa1[4], pa2[4];
            #pragma unroll
            for (int u = 0; u < 4; ++u) {
                const float* kr = Kt + (jj + u) * HD;
                float a1 = 0.f, a2 = 0.f;
                #pragma unroll
                for (int d4 = 0; d4 < 8; ++d4) {
                    float4 kv = ((const float4*)kr)[d4];
                    a1 += q1[d4*4+0]*kv.x + q1[d4*4+1]*kv.y + q1[d4*4+2]*kv.z + q1[d4*4+3]*kv.w;
                    a2 += q2[d4*4+0]*kv.x + q2[d4*4+1]*kv.y + q2[d4*4+2]*kv.z + q2[d4*4+3]*kv.w;
                }
                int jg = jt * 512 + jj + u;
                float s1 = (a1 + dl[tid + 1023 - jg]) * RS;
                float s2 = (a2 + dl[tid + 1279 - jg]) * RS;
                pa1[u] = __expf(s1 - m1) * rl1;
                pa2[u] = __expf(s2 - m2) * rl2;
            }
            int jg0 = jt * 512 + jj;
            *(float4*)&Ph[(size_t)(r0 + tid) * SS + jg0] =
                make_float4(pa1[0], pa1[1], pa1[2], pa1[3]);
            *(float4*)&Ph[(size_t)(r0 + 256 + tid) * SS + jg0] =
                make_float4(pa2[0], pa2[1], pa2[2], pa2[3]);
            #pragma unroll
            for (int u = 0; u < 4; ++u) {
                const float* vr = Vt + (jj + u) * HD;
                #pragma unroll
                for (int d4 = 0; d4 < 8; ++d4) {
                    float4 vv = ((const float4*)vr)[d4];
                    c1[d4*4+0] += pa1[u]*vv.x; c1[d4*4+1] += pa1[u]*vv.y;
                    c1[d4*4+2] += pa1[u]*vv.z; c1[d4*4+3] += pa1[u]*vv.w;
                    c2[d4*4+0] += pa2[u]*vv.x; c2[d4*4+1] += pa2[u]*vv.y;
                    c2[d4*4+2] += pa2[u]*vv.z; c2[d4*4+3] += pa2[u]*vv.w;
                }
            }
        }
    }

    // ctx written in (B, S, HID) layout
    float* cp1 = ctx + (size_t)(b * SS + r0 + tid) * HIDD + h * HD;
    float* cp2 = ctx + (size_t)(b * SS + r0 + 256 + tid) * HIDD + h * HD;
    #pragma unroll
    for (int d4 = 0; d4 < 8; ++d4) {
        ((float4*)cp1)[d4] = make_float4(c1[d4*4], c1[d4*4+1], c1[d4*4+2], c1[d4*4+3]);
        ((float4*)cp2)[d4] = make_float4(c2[d4*4], c2[d4*4+1], c2[d4*4+2], c2[d4*4+3]);
    }
}

// ---------------------------------------------------------------------------
// Row LayerNorm: one block (256 threads) per row of 1024.
// ---------------------------------------------------------------------------
__global__ __launch_bounds__(256) void ln_kernel(
    const float* __restrict__ X, const float* __restrict__ gamma,
    const float* __restrict__ beta, float* __restrict__ out)
{
    const int row = blockIdx.x;
    const int tid = threadIdx.x;
    const float* xr = X + (size_t)row * 1024;
    float4 x = *(const float4*)&xr[tid * 4];
    float s = x.x + x.y + x.z + x.w;
    float q = x.x*x.x + x.y*x.y + x.z*x.z + x.w*x.w;
    #pragma unroll
    for (int off = 32; off; off >>= 1) {
        s += __shfl_xor(s, off);
        q += __shfl_xor(q, off);
    }
    __shared__ float ps[4], pq[4];
    int wid = tid >> 6, lane = tid & 63;
    if (lane == 0) { ps[wid] = s; pq[wid] = q; }
    __syncthreads();
    s = ps[0] + ps[1] + ps[2] + ps[3];
    q = pq[0] + pq[1] + pq[2] + pq[3];
    float mu = s * (1.0f / 1024.0f);
    float var = q * (1.0f / 1024.0f) - mu * mu;
    float rstd = 1.0f / sqrtf(var + 1e-12f);
    float4 g = *(const float4*)&gamma[tid * 4];
    float4 bt = *(const float4*)&beta[tid * 4];
    float4 o;
    o.x = (x.x - mu) * rstd * g.x + bt.x;
    o.y = (x.y - mu) * rstd * g.y + bt.y;
    o.z = (x.z - mu) * rstd * g.z + bt.z;
    o.w = (x.w - mu) * rstd * g.w + bt.w;
    *(float4*)&out[(size_t)row * 1024 + tid * 4] = o;
}

// ---------------------------------------------------------------------------
extern "C" void kernel_launch(void* const* d_in, const int* in_sizes, int n_in,
                              void* d_out, int out_size, void* d_ws, size_t ws_size,
                              hipStream_t stream)
{
    const float* hid  = (const float*)d_in[0];
    const float* Wq   = (const float*)d_in[1];
    const float* bq   = (const float*)d_in[2];
    const float* Wk   = (const float*)d_in[3];
    const float* bk   = (const float*)d_in[4];
    const float* Wv   = (const float*)d_in[5];
    const float* bvv  = (const float*)d_in[6];
    const float* Wo   = (const float*)d_in[7];
    const float* bo   = (const float*)d_in[8];
    const float* lng  = (const float*)d_in[9];
    const float* lnb  = (const float*)d_in[10];
    const float* dist = (const float*)d_in[11];

    float* out   = (float*)d_out;
    float* probs = out + (size_t)BB * SS * HIDD;   // 4,194,304 offset

    const size_t QN = (size_t)BB * NH * SS * HD;   // 4M floats
    float* ws   = (float*)d_ws;
    float* Qb   = ws;
    float* Kb   = ws + QN;
    float* Vb   = ws + 2 * QN;
    float* ctxb = ws + 3 * QN;
    float* xres = ws;                              // reuse Qb after attention

    gemm_qkv<<<dim3(32, 8, 3), 256, 0, stream>>>(hid, Wq, Wk, Wv, bq, bk, bvv, Qb, Kb, Vb);
    attn_kernel<<<dim3(2, NH, BB), 256, 0, stream>>>(Qb, Kb, Vb, dist, probs, ctxb);
    gemm_out<<<dim3(32, 8), 256, 0, stream>>>(ctxb, Wo, bo, hid, xres);
    ln_kernel<<<4096, 256, 0, stream>>>(xres, lng, lnb, out);
}